// Round 5
// baseline (133.821 us; speedup 1.0000x reference)
//
#include <hip/hip_runtime.h>
#include <math.h>

// Problem constants
#define B_    4
#define T_    2048
#define D_    512
#define H_    4
#define ROWS_ 8192
#define CHSZ_ 128     // timesteps per chunk
#define NCHK_ 16      // chunks per (b,h)

typedef unsigned short ushort_t;
typedef unsigned int   uint_t;
typedef __attribute__((ext_vector_type(8))) __bf16         bfx8;
typedef __attribute__((ext_vector_type(8))) unsigned short u16x8;
typedef __attribute__((ext_vector_type(4))) float          fx4;

__device__ __forceinline__ ushort_t f2bf(float f) {
    union { float f; uint_t u; } v; v.f = f;
    return (ushort_t)((v.u + 0x7FFFu + ((v.u >> 16) & 1u)) >> 16);
}
__device__ __forceinline__ float bf2f(ushort_t u) {
    union { uint_t u; float f; } v; v.u = ((uint_t)u) << 16; return v.f;
}

// ---------------------------------------------------------------------------
// prep_pack: blocks [0,2048): per-wave row prep (x->xbf bf16, fp32-exact
// a = -softplus(x·Wa+ba)); blocks [2048,2688): weight pack (head-major WcatT2,
// transposed WoT); block 2688: zero look-back flags (ws is 0xAA-poisoned).
// ---------------------------------------------------------------------------
__global__ __launch_bounds__(256) void prep_pack(const float* __restrict__ x,
                                                 const float* __restrict__ Wa,
                                                 const float* __restrict__ ba,
                                                 const float* __restrict__ Wq,
                                                 const float* __restrict__ Wk,
                                                 const float* __restrict__ Wv,
                                                 const float* __restrict__ Wg,
                                                 const float* __restrict__ Wo,
                                                 ushort_t* __restrict__ xbf,
                                                 float* __restrict__ Aarr,
                                                 ushort_t* __restrict__ WcatT2,
                                                 ushort_t* __restrict__ WoT,
                                                 int* __restrict__ flags) {
    const int blk = blockIdx.x;
    if (blk < 2048) {
        const int wave = threadIdx.x >> 6, lane = threadIdx.x & 63;
        const int row = blk * 4 + wave;
        const float* xp = x + (size_t)row * D_ + lane * 8;
        float4 f0 = *(const float4*)xp;
        float4 f1 = *(const float4*)(xp + 4);
        float xv[8] = {f0.x, f0.y, f0.z, f0.w, f1.x, f1.y, f1.z, f1.w};

        u16x8 u;
        #pragma unroll
        for (int j = 0; j < 8; j++) u[j] = f2bf(xv[j]);
        *(u16x8*)(xbf + (size_t)row * D_ + lane * 8) = u;

        float a0 = 0.f, a1 = 0.f, a2 = 0.f, a3 = 0.f;
        #pragma unroll
        for (int j = 0; j < 8; j++) {
            float4 w = *(const float4*)&Wa[(size_t)(lane * 8 + j) * 4];
            a0 = fmaf(xv[j], w.x, a0);
            a1 = fmaf(xv[j], w.y, a1);
            a2 = fmaf(xv[j], w.z, a2);
            a3 = fmaf(xv[j], w.w, a3);
        }
        #pragma unroll
        for (int off = 32; off; off >>= 1) {
            a0 += __shfl_xor(a0, off);
            a1 += __shfl_xor(a1, off);
            a2 += __shfl_xor(a2, off);
            a3 += __shfl_xor(a3, off);
        }
        if (lane == 0) {
            float z[4] = {a0 + ba[0], a1 + ba[1], a2 + ba[2], a3 + ba[3]};
            float r[4];
            #pragma unroll
            for (int h = 0; h < 4; h++)
                r[h] = -(fmaxf(z[h], 0.f) + log1pf(expf(-fabsf(z[h]))));
            *(float4*)&Aarr[(size_t)row * 4] = make_float4(r[0], r[1], r[2], r[3]);
        }
    } else if (blk < 2688) {
        int idx = (blk - 2048) * 256 + threadIdx.x;
        if (idx < 256 * 512) {
            int n = idx >> 9, d = idx & 511;
            int h = n >> 6, r = n & 63, part = r >> 4, j = r & 15;
            int col = h * 16 + j;
            const float* W = (part == 0) ? Wq : (part == 1) ? Wk : (part == 2) ? Wv : Wg;
            WcatT2[idx] = f2bf(W[(size_t)d * 64 + col]);
        } else {
            int r = idx - 256 * 512;          // 0..32767 = n*64 + k
            int n = r >> 6, k = r & 63;
            WoT[r] = f2bf(Wo[(size_t)k * 512 + n]);
        }
    } else {
        flags[threadIdx.x] = 0;               // 256 flags
    }
}

// ---------------------------------------------------------------------------
// gemm_scan: fused projection GEMM (128x64 tile, K=512) + chunk scan +
// decoupled look-back + gated output. Grid: 256 = 64 row-chunks x 4 heads.
//
// Scan normalization is PER-WAVE max (lg increases ~0.7/step, so a 128-row
// chunk max would underflow e^{lg-Mc} for early rows — R4's NaN). Within a
// 64-row wave the spread is ~48 << 87, so e^{lg-Mw} is a normal float and
// every row's prefix denominator is > 0. Wave 1 merges wave 0's totals with
// one exact max-aware combine; rows carry their frame myM (M0 or Mc) into
// the final combine with the look-back prefix.
// ---------------------------------------------------------------------------
__global__ __launch_bounds__(256) void gemm_scan(const ushort_t* __restrict__ xbf,
                                                 const ushort_t* __restrict__ WcatT2,
                                                 const float* __restrict__ Aarr,
                                                 const float* __restrict__ bg,
                                                 float* __restrict__ slots,
                                                 int* __restrict__ flags,
                                                 ushort_t* __restrict__ Ybf) {
    __shared__ ushort_t As[128 * 72];   // reused as Ct after K-loop
    __shared__ ushort_t Bs[64 * 72];
    __shared__ float s_a0;
    __shared__ float s_wmax[2];
    __shared__ float s_tot[17];
    __shared__ float s_pref[18];

    const int rc = blockIdx.x & 63;     // row chunk (b*16 + chunk)
    const int h  = blockIdx.x >> 6;
    const int m0 = rc * 128;
    const int n0 = h * 64;
    const int b  = rc >> 4, chunk = rc & 15;
    const int bh = b * 4 + h;

    const int tid = threadIdx.x;
    const int wave = tid >> 6, lane = tid & 63;
    const int fr = lane & 15, quad = lane >> 4;
    const int sr = tid >> 3, sc = (tid & 7) * 8;

    fx4 acc[2][4];
    #pragma unroll
    for (int i = 0; i < 2; i++)
        #pragma unroll
        for (int j = 0; j < 4; j++) acc[i][j] = (fx4)0.f;

    for (int k0 = 0; k0 < D_; k0 += 64) {
        #pragma unroll
        for (int s = 0; s < 4; s++) {
            int r = s * 32 + sr;
            *(u16x8*)&As[r * 72 + sc] = *(const u16x8*)(xbf + (size_t)(m0 + r) * D_ + k0 + sc);
        }
        #pragma unroll
        for (int s = 0; s < 2; s++) {
            int r = s * 32 + sr;
            *(u16x8*)&Bs[r * 72 + sc] = *(const u16x8*)(WcatT2 + (size_t)(n0 + r) * D_ + k0 + sc);
        }
        __syncthreads();
        #pragma unroll
        for (int ks = 0; ks < 64; ks += 32) {
            bfx8 af[2], bfr[4];
            #pragma unroll
            for (int mi = 0; mi < 2; mi++)
                af[mi] = *(const bfx8*)&As[(wave * 32 + mi * 16 + fr) * 72 + ks + quad * 8];
            #pragma unroll
            for (int ni = 0; ni < 4; ni++)
                bfr[ni] = *(const bfx8*)&Bs[(ni * 16 + fr) * 72 + ks + quad * 8];
            #pragma unroll
            for (int mi = 0; mi < 2; mi++)
                #pragma unroll
                for (int ni = 0; ni < 4; ni++)
                    acc[mi][ni] = __builtin_amdgcn_mfma_f32_16x16x32_bf16(af[mi], bfr[ni], acc[mi][ni], 0, 0, 0);
        }
        __syncthreads();
    }

    // C-tile (bf16) into As-as-Ct: row_local x 72 stride, cols 0..63
    #pragma unroll
    for (int mi = 0; mi < 2; mi++)
        #pragma unroll
        for (int ni = 0; ni < 4; ni++)
            #pragma unroll
            for (int r = 0; r < 4; r++) {
                int rl = wave * 32 + mi * 16 + quad * 4 + r;
                int cl = ni * 16 + fr;
                As[rl * 72 + cl] = f2bf(acc[mi][ni][r]);
            }
    __syncthreads();

    // ---- chunk-local scan: threads 0..127 (waves 0,1), one per row ----
    const bool active = (tid < 128);
    float bid = 0.f, a = 0.f;
    float v[16];
    if (active) {
        const ushort_t* ct = &As[tid * 72];
        u16x8 q0 = *(const u16x8*)(ct +  0), q1 = *(const u16x8*)(ct +  8);
        u16x8 k0 = *(const u16x8*)(ct + 16), k1 = *(const u16x8*)(ct + 24);
        u16x8 v0 = *(const u16x8*)(ct + 32), v1 = *(const u16x8*)(ct + 40);
        #pragma unroll
        for (int j = 0; j < 8; j++) {
            bid = fmaf(bf2f(q0[j]), bf2f(k0[j]), bid);
            bid = fmaf(bf2f(q1[j]), bf2f(k1[j]), bid);
            v[j]     = bf2f(v0[j]);
            v[8 + j] = bf2f(v1[j]);
        }
        bid *= 0.25f;
        a = Aarr[(size_t)(m0 + tid) * 4 + h];
    }

    // cumA inclusive scan over 128 rows (2 waves + LDS bridge)
    float ca = a;
    #pragma unroll
    for (int off = 1; off < 64; off <<= 1) {
        float up = __shfl_up(ca, off);
        if (lane >= off) ca += up;
    }
    if (tid == 63) s_a0 = ca;
    __syncthreads();
    if (active && wave == 1) ca += s_a0;

    float lg = bid - ca;      // chunk-local log-weight (increases with t)

    // per-wave max Mw (frame for this wave's prefix sums)
    float Mw = active ? lg : -1e30f;
    #pragma unroll
    for (int off = 32; off; off >>= 1) Mw = fmaxf(Mw, __shfl_xor(Mw, off));
    if (active && lane == 0) s_wmax[wave] = Mw;
    __syncthreads();
    const float M0 = s_wmax[0], M1 = s_wmax[1];
    const float Mc = fmaxf(M0, M1);

    // plain prefix sums of (d, n[16]) = e^{lg-Mw} * (1, v) within wave
    float d = active ? __expf(lg - Mw) : 0.f;
    float n[16];
    #pragma unroll
    for (int j = 0; j < 16; j++) n[j] = d * v[j];
    #pragma unroll
    for (int off = 1; off < 64; off <<= 1) {
        float ud = __shfl_up(d, off);
        float un[16];
        #pragma unroll
        for (int j = 0; j < 16; j++) un[j] = __shfl_up(n[j], off);
        if (lane >= off) {
            d += ud;
            #pragma unroll
            for (int j = 0; j < 16; j++) n[j] += un[j];
        }
    }
    // wave-0 totals -> LDS (frame M0)
    if (tid == 63) {
        s_tot[0] = d;
        #pragma unroll
        for (int j = 0; j < 16; j++) s_tot[1 + j] = n[j];
    }
    __syncthreads();
    // wave-1 rows merge wave-0 totals (result frame Mc)
    if (active && wave == 1) {
        float al = __expf(M0 - Mc), be = __expf(M1 - Mc);
        d = s_tot[0] * al + d * be;
        #pragma unroll
        for (int j = 0; j < 16; j++) n[j] = s_tot[1 + j] * al + n[j] * be;
    }
    const float myM = (wave == 0) ? M0 : Mc;   // frame of this row's (d,n)

    // publish chunk aggregate (thread 127: merged totals, frame Mc; ca = aTot)
    if (tid == 127) {
        float* sl = slots + (size_t)(bh * NCHK_ + chunk) * 20;
        sl[0] = Mc; sl[1] = d;
        #pragma unroll
        for (int j = 0; j < 16; j++) sl[2 + j] = n[j];
        sl[18] = ca;
        __threadfence();
        __hip_atomic_store(&flags[bh * NCHK_ + chunk], 1,
                           __ATOMIC_RELEASE, __HIP_MEMORY_SCOPE_AGENT);
    }

    // ---- look-back: wave 0, lane p handles predecessor chunk p ----
    if (wave == 0) {
        float mf = -1e30f, dd = 0.f, aT = 0.f;
        float nn[16];
        #pragma unroll
        for (int j = 0; j < 16; j++) nn[j] = 0.f;
        if (lane < chunk) {
            const int sidx = bh * NCHK_ + lane;
            while (__hip_atomic_load(&flags[sidx],
                                     __ATOMIC_ACQUIRE, __HIP_MEMORY_SCOPE_AGENT) == 0) {}
            const float* sl = slots + (size_t)sidx * 20;
            mf = sl[0]; dd = sl[1];
            #pragma unroll
            for (int j = 0; j < 16; j++) nn[j] = sl[2 + j];
            aT = sl[18];
        }
        // suffix sums of aTot: off_p = sum_{q=p}^{chunk-1} aT_q
        float off = aT;
        #pragma unroll
        for (int s = 1; s < 16; s <<= 1) {
            float t2 = __shfl_down(off, s);
            if (lane + s < chunk) off += t2;
        }
        if (lane < chunk) mf += off;   // convert to this chunk's local frame
        // tree-combine lanes 0..15 (softmax merge; -1e30 is identity)
        #pragma unroll
        for (int s = 1; s < 16; s <<= 1) {
            float m2 = __shfl_xor(mf, s);
            float d2 = __shfl_xor(dd, s);
            float mn = fmaxf(mf, m2);
            float al = __expf(mf - mn), be = __expf(m2 - mn);
            #pragma unroll
            for (int j = 0; j < 16; j++) {
                float n2 = __shfl_xor(nn[j], s);
                nn[j] = nn[j] * al + n2 * be;
            }
            dd = dd * al + d2 * be;
            mf = mn;
        }
        if (lane == 0) {
            s_pref[0] = mf; s_pref[1] = dd;
            #pragma unroll
            for (int j = 0; j < 16; j++) s_pref[2 + j] = nn[j];
        }
    }
    __syncthreads();

    // ---- combine prefix with per-row state, gate, write Ybf ----
    if (active) {
        const float M = s_pref[0], D = s_pref[1];
        const float mn = fmaxf(M, myM);
        const float al = __expf(M - mn), be = __expf(myM - mn);
        const float invd = 1.f / (D * al + d * be);

        const ushort_t* ct = &As[tid * 72];
        u16x8 g0 = *(const u16x8*)(ct + 48), g1 = *(const u16x8*)(ct + 56);
        u16x8 o0, o1;
        #pragma unroll
        for (int j = 0; j < 16; j++) {
            float Nj = s_pref[2 + j] * al + n[j] * be;
            float gpre = ((j < 8) ? bf2f(g0[j]) : bf2f(g1[j - 8])) + bg[h * 16 + j];
            float gate = 1.f / (1.f + __expf(-gpre));
            ushort_t yb = f2bf(Nj * invd * gate);
            if (j < 8) o0[j] = yb; else o1[j - 8] = yb;
        }
        const size_t row = (size_t)b * T_ + chunk * CHSZ_ + tid;
        *(u16x8*)(Ybf + row * 64 + h * 16)     = o0;
        *(u16x8*)(Ybf + row * 64 + h * 16 + 8) = o1;
    }
}

// ---------------------------------------------------------------------------
// Output GEMM: C(MxN) = A(MxK) @ BT(NxK)^T, bf16 MFMA. BM=64 BN=128 BK=64.
// ---------------------------------------------------------------------------
__global__ __launch_bounds__(256) void gemm_bt(const ushort_t* __restrict__ A,
                                               const ushort_t* __restrict__ BT,
                                               float* __restrict__ C,
                                               int M, int N, int K) {
    __shared__ ushort_t As[64 * 72];
    __shared__ ushort_t Bs[128 * 72];
    const int tid = threadIdx.x;
    const int wave = tid >> 6, lane = tid & 63;
    const int m0 = blockIdx.y * 64, n0 = blockIdx.x * 128;
    const int wr = wave >> 1, wc = wave & 1;

    fx4 acc[2][4];
    #pragma unroll
    for (int i = 0; i < 2; i++)
        #pragma unroll
        for (int j = 0; j < 4; j++) acc[i][j] = (fx4)0.f;

    const int sr = tid >> 3, sc = (tid & 7) * 8;

    for (int k0 = 0; k0 < K; k0 += 64) {
        #pragma unroll
        for (int s = 0; s < 2; s++) {
            int r = s * 32 + sr;
            *(u16x8*)&As[r * 72 + sc] = *(const u16x8*)(A + (size_t)(m0 + r) * K + k0 + sc);
        }
        #pragma unroll
        for (int s = 0; s < 4; s++) {
            int r = s * 32 + sr;
            *(u16x8*)&Bs[r * 72 + sc] = *(const u16x8*)(BT + (size_t)(n0 + r) * K + k0 + sc);
        }
        __syncthreads();
        const int fr = lane & 15, quad = lane >> 4;
        #pragma unroll
        for (int ks = 0; ks < 64; ks += 32) {
            bfx8 af[2], bfr[4];
            #pragma unroll
            for (int mi = 0; mi < 2; mi++)
                af[mi] = *(const bfx8*)&As[(wr * 32 + mi * 16 + fr) * 72 + ks + quad * 8];
            #pragma unroll
            for (int ni = 0; ni < 4; ni++)
                bfr[ni] = *(const bfx8*)&Bs[(wc * 64 + ni * 16 + fr) * 72 + ks + quad * 8];
            #pragma unroll
            for (int mi = 0; mi < 2; mi++)
                #pragma unroll
                for (int ni = 0; ni < 4; ni++)
                    acc[mi][ni] = __builtin_amdgcn_mfma_f32_16x16x32_bf16(af[mi], bfr[ni], acc[mi][ni], 0, 0, 0);
        }
        __syncthreads();
    }

    const int fr = lane & 15, quad = lane >> 4;
    #pragma unroll
    for (int mi = 0; mi < 2; mi++)
        #pragma unroll
        for (int ni = 0; ni < 4; ni++)
            #pragma unroll
            for (int r = 0; r < 4; r++) {
                int rr = m0 + wr * 32 + mi * 16 + quad * 4 + r;
                int cc = n0 + wc * 64 + ni * 16 + fr;
                C[(size_t)rr * N + cc] = acc[mi][ni][r];
            }
}

// ---------------------------------------------------------------------------
extern "C" void kernel_launch(void* const* d_in, const int* in_sizes, int n_in,
                              void* d_out, int out_size, void* d_ws, size_t ws_size,
                              hipStream_t stream) {
    const float* x  = (const float*)d_in[0];
    const float* Wq = (const float*)d_in[1];
    const float* Wk = (const float*)d_in[2];
    const float* Wv = (const float*)d_in[3];
    const float* Wa = (const float*)d_in[4];
    const float* ba = (const float*)d_in[5];
    const float* Wg = (const float*)d_in[6];
    const float* bg = (const float*)d_in[7];
    const float* Wo = (const float*)d_in[8];
    float* out = (float*)d_out;

    char* w = (char*)d_ws;
    ushort_t* xbf    = (ushort_t*)w;  w += (size_t)ROWS_ * D_ * 2;   // 8 MiB
    ushort_t* WcatT2 = (ushort_t*)w;  w += 256 * 512 * 2;            // 256 KiB
    ushort_t* WoT    = (ushort_t*)w;  w += 512 * 64 * 2;             // 64 KiB
    float*    Aarr   = (float*)w;     w += (size_t)ROWS_ * 4 * 4;    // 128 KiB
    float*    slots  = (float*)w;     w += 256 * 20 * 4;             // 20 KiB
    int*      flags  = (int*)w;       w += 256 * 4;                  // 1 KiB
    ushort_t* Ybf    = (ushort_t*)w;  w += (size_t)ROWS_ * 64 * 2;   // 1 MiB

    prep_pack<<<2689, 256, 0, stream>>>(x, Wa, ba, Wq, Wk, Wv, Wg, Wo,
                                        xbf, Aarr, WcatT2, WoT, flags);
    gemm_scan<<<256, 256, 0, stream>>>(xbf, WcatT2, Aarr, bg, slots, flags, Ybf);
    gemm_bt<<<dim3(4, 128), 256, 0, stream>>>(Ybf, WoT, out, ROWS_, D_, 64);
}

// Round 6
// 119.775 us; speedup vs baseline: 1.1173x; 1.1173x over previous
//
#include <hip/hip_runtime.h>
#include <math.h>

// Problem constants
#define B_    4
#define T_    2048
#define D_    512
#define H_    4
#define ROWS_ 8192
#define CHSZ_ 128     // timesteps per chunk
#define NCHK_ 16      // chunks per (b,h)

typedef unsigned short ushort_t;
typedef unsigned int   uint_t;
typedef __attribute__((ext_vector_type(8))) __bf16         bfx8;
typedef __attribute__((ext_vector_type(8))) unsigned short u16x8;
typedef __attribute__((ext_vector_type(4))) float          fx4;

__device__ __forceinline__ ushort_t f2bf(float f) {
    union { float f; uint_t u; } v; v.f = f;
    return (ushort_t)((v.u + 0x7FFFu + ((v.u >> 16) & 1u)) >> 16);
}
__device__ __forceinline__ float bf2f(ushort_t u) {
    union { uint_t u; float f; } v; v.u = ((uint_t)u) << 16; return v.f;
}

// relaxed agent-scope atomics: L2-bypassing, LLC-coherent, NO buffer_inv/wbl2
__device__ __forceinline__ void st_rlx(float* p, float v) {
    __hip_atomic_store(p, v, __ATOMIC_RELAXED, __HIP_MEMORY_SCOPE_AGENT);
}
__device__ __forceinline__ float ld_rlx(const float* p) {
    return __hip_atomic_load(p, __ATOMIC_RELAXED, __HIP_MEMORY_SCOPE_AGENT);
}

// ---------------------------------------------------------------------------
// prep_pack: blocks [0,2048): per-wave row prep (x->xbf bf16, fp32-exact
// a = -softplus(x·Wa+ba)); blocks [2048,2688): weight pack (head-major WcatT2,
// transposed WoT); block 2688: zero look-back flags (ws is 0xAA-poisoned).
// EOP cache flush at kernel end makes these visible to gemm_scan's
// bypassing atomics.
// ---------------------------------------------------------------------------
__global__ __launch_bounds__(256) void prep_pack(const float* __restrict__ x,
                                                 const float* __restrict__ Wa,
                                                 const float* __restrict__ ba,
                                                 const float* __restrict__ Wq,
                                                 const float* __restrict__ Wk,
                                                 const float* __restrict__ Wv,
                                                 const float* __restrict__ Wg,
                                                 const float* __restrict__ Wo,
                                                 ushort_t* __restrict__ xbf,
                                                 float* __restrict__ Aarr,
                                                 ushort_t* __restrict__ WcatT2,
                                                 ushort_t* __restrict__ WoT,
                                                 int* __restrict__ flags) {
    const int blk = blockIdx.x;
    if (blk < 2048) {
        const int wave = threadIdx.x >> 6, lane = threadIdx.x & 63;
        const int row = blk * 4 + wave;
        const float* xp = x + (size_t)row * D_ + lane * 8;
        float4 f0 = *(const float4*)xp;
        float4 f1 = *(const float4*)(xp + 4);
        float xv[8] = {f0.x, f0.y, f0.z, f0.w, f1.x, f1.y, f1.z, f1.w};

        u16x8 u;
        #pragma unroll
        for (int j = 0; j < 8; j++) u[j] = f2bf(xv[j]);
        *(u16x8*)(xbf + (size_t)row * D_ + lane * 8) = u;

        float a0 = 0.f, a1 = 0.f, a2 = 0.f, a3 = 0.f;
        #pragma unroll
        for (int j = 0; j < 8; j++) {
            float4 w = *(const float4*)&Wa[(size_t)(lane * 8 + j) * 4];
            a0 = fmaf(xv[j], w.x, a0);
            a1 = fmaf(xv[j], w.y, a1);
            a2 = fmaf(xv[j], w.z, a2);
            a3 = fmaf(xv[j], w.w, a3);
        }
        #pragma unroll
        for (int off = 32; off; off >>= 1) {
            a0 += __shfl_xor(a0, off);
            a1 += __shfl_xor(a1, off);
            a2 += __shfl_xor(a2, off);
            a3 += __shfl_xor(a3, off);
        }
        if (lane == 0) {
            float z[4] = {a0 + ba[0], a1 + ba[1], a2 + ba[2], a3 + ba[3]};
            float r[4];
            #pragma unroll
            for (int h = 0; h < 4; h++)
                r[h] = -(fmaxf(z[h], 0.f) + log1pf(expf(-fabsf(z[h]))));
            *(float4*)&Aarr[(size_t)row * 4] = make_float4(r[0], r[1], r[2], r[3]);
        }
    } else if (blk < 2688) {
        int idx = (blk - 2048) * 256 + threadIdx.x;
        if (idx < 256 * 512) {
            int n = idx >> 9, d = idx & 511;
            int h = n >> 6, r = n & 63, part = r >> 4, j = r & 15;
            int col = h * 16 + j;
            const float* W = (part == 0) ? Wq : (part == 1) ? Wk : (part == 2) ? Wv : Wg;
            WcatT2[idx] = f2bf(W[(size_t)d * 64 + col]);
        } else {
            int r = idx - 256 * 512;          // 0..32767 = n*64 + k
            int n = r >> 6, k = r & 63;
            WoT[r] = f2bf(Wo[(size_t)k * 512 + n]);
        }
    } else {
        flags[threadIdx.x] = 0;               // 256 flags
    }
}

// ---------------------------------------------------------------------------
// gemm_scan: fused projection GEMM (128x64 tile, K=512) + chunk scan +
// decoupled look-back + gated output. Grid: 256 = 64 row-chunks x 4 heads.
//
// Scan normalization is PER-WAVE max (lg increases ~0.7/step; a 128-row
// chunk max underflows early rows — R4's NaN). Look-back protocol uses ONLY
// relaxed agent-scope atomics (no acquire/release → no buffer_inv/buffer_wbl2
// L2-maintenance storm, which made R5's gemm_scan 95% stall). Ordering:
// slot stores → s_waitcnt vmcnt(0) → flag store (write-through message
// passing; all slot/flag accesses everywhere are bypassing atomics).
// ---------------------------------------------------------------------------
__global__ __launch_bounds__(256) void gemm_scan(const ushort_t* __restrict__ xbf,
                                                 const ushort_t* __restrict__ WcatT2,
                                                 const float* __restrict__ Aarr,
                                                 const float* __restrict__ bg,
                                                 float* __restrict__ slots,
                                                 int* __restrict__ flags,
                                                 ushort_t* __restrict__ Ybf) {
    __shared__ ushort_t As[128 * 72];   // reused as Ct after K-loop
    __shared__ ushort_t Bs[64 * 72];
    __shared__ float s_a0;
    __shared__ float s_wmax[2];
    __shared__ float s_tot[17];
    __shared__ float s_pref[18];

    const int rc = blockIdx.x & 63;     // row chunk (b*16 + chunk)
    const int h  = blockIdx.x >> 6;
    const int m0 = rc * 128;
    const int n0 = h * 64;
    const int b  = rc >> 4, chunk = rc & 15;
    const int bh = b * 4 + h;

    const int tid = threadIdx.x;
    const int wave = tid >> 6, lane = tid & 63;
    const int fr = lane & 15, quad = lane >> 4;
    const int sr = tid >> 3, sc = (tid & 7) * 8;

    fx4 acc[2][4];
    #pragma unroll
    for (int i = 0; i < 2; i++)
        #pragma unroll
        for (int j = 0; j < 4; j++) acc[i][j] = (fx4)0.f;

    for (int k0 = 0; k0 < D_; k0 += 64) {
        #pragma unroll
        for (int s = 0; s < 4; s++) {
            int r = s * 32 + sr;
            *(u16x8*)&As[r * 72 + sc] = *(const u16x8*)(xbf + (size_t)(m0 + r) * D_ + k0 + sc);
        }
        #pragma unroll
        for (int s = 0; s < 2; s++) {
            int r = s * 32 + sr;
            *(u16x8*)&Bs[r * 72 + sc] = *(const u16x8*)(WcatT2 + (size_t)(n0 + r) * D_ + k0 + sc);
        }
        __syncthreads();
        #pragma unroll
        for (int ks = 0; ks < 64; ks += 32) {
            bfx8 af[2], bfr[4];
            #pragma unroll
            for (int mi = 0; mi < 2; mi++)
                af[mi] = *(const bfx8*)&As[(wave * 32 + mi * 16 + fr) * 72 + ks + quad * 8];
            #pragma unroll
            for (int ni = 0; ni < 4; ni++)
                bfr[ni] = *(const bfx8*)&Bs[(ni * 16 + fr) * 72 + ks + quad * 8];
            #pragma unroll
            for (int mi = 0; mi < 2; mi++)
                #pragma unroll
                for (int ni = 0; ni < 4; ni++)
                    acc[mi][ni] = __builtin_amdgcn_mfma_f32_16x16x32_bf16(af[mi], bfr[ni], acc[mi][ni], 0, 0, 0);
        }
        __syncthreads();
    }

    // C-tile (bf16) into As-as-Ct: row_local x 72 stride, cols 0..63
    #pragma unroll
    for (int mi = 0; mi < 2; mi++)
        #pragma unroll
        for (int ni = 0; ni < 4; ni++)
            #pragma unroll
            for (int r = 0; r < 4; r++) {
                int rl = wave * 32 + mi * 16 + quad * 4 + r;
                int cl = ni * 16 + fr;
                As[rl * 72 + cl] = f2bf(acc[mi][ni][r]);
            }
    __syncthreads();

    // ---- chunk-local scan: threads 0..127 (waves 0,1), one per row ----
    const bool active = (tid < 128);
    float bid = 0.f, a = 0.f;
    float v[16];
    if (active) {
        const ushort_t* ct = &As[tid * 72];
        u16x8 q0 = *(const u16x8*)(ct +  0), q1 = *(const u16x8*)(ct +  8);
        u16x8 k0 = *(const u16x8*)(ct + 16), k1 = *(const u16x8*)(ct + 24);
        u16x8 v0 = *(const u16x8*)(ct + 32), v1 = *(const u16x8*)(ct + 40);
        #pragma unroll
        for (int j = 0; j < 8; j++) {
            bid = fmaf(bf2f(q0[j]), bf2f(k0[j]), bid);
            bid = fmaf(bf2f(q1[j]), bf2f(k1[j]), bid);
            v[j]     = bf2f(v0[j]);
            v[8 + j] = bf2f(v1[j]);
        }
        bid *= 0.25f;
        a = Aarr[(size_t)(m0 + tid) * 4 + h];
    }

    // cumA inclusive scan over 128 rows (2 waves + LDS bridge)
    float ca = a;
    #pragma unroll
    for (int off = 1; off < 64; off <<= 1) {
        float up = __shfl_up(ca, off);
        if (lane >= off) ca += up;
    }
    if (tid == 63) s_a0 = ca;
    __syncthreads();
    if (active && wave == 1) ca += s_a0;

    float lg = bid - ca;      // chunk-local log-weight (increases with t)

    // per-wave max Mw (frame for this wave's prefix sums)
    float Mw = active ? lg : -1e30f;
    #pragma unroll
    for (int off = 32; off; off >>= 1) Mw = fmaxf(Mw, __shfl_xor(Mw, off));
    if (active && lane == 0) s_wmax[wave] = Mw;
    __syncthreads();
    const float M0 = s_wmax[0], M1 = s_wmax[1];
    const float Mc = fmaxf(M0, M1);

    // plain prefix sums of (d, n[16]) = e^{lg-Mw} * (1, v) within wave
    float d = active ? __expf(lg - Mw) : 0.f;
    float n[16];
    #pragma unroll
    for (int j = 0; j < 16; j++) n[j] = d * v[j];
    #pragma unroll
    for (int off = 1; off < 64; off <<= 1) {
        float ud = __shfl_up(d, off);
        float un[16];
        #pragma unroll
        for (int j = 0; j < 16; j++) un[j] = __shfl_up(n[j], off);
        if (lane >= off) {
            d += ud;
            #pragma unroll
            for (int j = 0; j < 16; j++) n[j] += un[j];
        }
    }
    // wave-0 totals -> LDS (frame M0)
    if (tid == 63) {
        s_tot[0] = d;
        #pragma unroll
        for (int j = 0; j < 16; j++) s_tot[1 + j] = n[j];
    }
    __syncthreads();
    // wave-1 rows merge wave-0 totals (result frame Mc)
    if (active && wave == 1) {
        float al = __expf(M0 - Mc), be = __expf(M1 - Mc);
        d = s_tot[0] * al + d * be;
        #pragma unroll
        for (int j = 0; j < 16; j++) n[j] = s_tot[1 + j] * al + n[j] * be;
    }
    const float myM = (wave == 0) ? M0 : Mc;   // frame of this row's (d,n)

    // publish chunk aggregate (thread 127: merged totals, frame Mc; ca = aTot)
    if (tid == 127) {
        float* sl = slots + (size_t)(bh * NCHK_ + chunk) * 20;
        st_rlx(&sl[0], Mc);
        st_rlx(&sl[1], d);
        #pragma unroll
        for (int j = 0; j < 16; j++) st_rlx(&sl[2 + j], n[j]);
        st_rlx(&sl[18], ca);
        asm volatile("s_waitcnt vmcnt(0)" ::: "memory");   // slots at LLC before flag
        __hip_atomic_store(&flags[bh * NCHK_ + chunk], 1,
                           __ATOMIC_RELAXED, __HIP_MEMORY_SCOPE_AGENT);
    }

    // ---- look-back: wave 0, lane p handles predecessor chunk p ----
    if (wave == 0) {
        float mf = -1e30f, dd = 0.f, aT = 0.f;
        float nn[16];
        #pragma unroll
        for (int j = 0; j < 16; j++) nn[j] = 0.f;
        if (lane < chunk) {
            const int sidx = bh * NCHK_ + lane;
            while (__hip_atomic_load(&flags[sidx],
                                     __ATOMIC_RELAXED, __HIP_MEMORY_SCOPE_AGENT) == 0) {
                __builtin_amdgcn_s_sleep(1);
            }
            const float* sl = slots + (size_t)sidx * 20;
            mf = ld_rlx(&sl[0]);
            dd = ld_rlx(&sl[1]);
            #pragma unroll
            for (int j = 0; j < 16; j++) nn[j] = ld_rlx(&sl[2 + j]);
            aT = ld_rlx(&sl[18]);
        }
        // suffix sums of aTot: off_p = sum_{q=p}^{chunk-1} aT_q
        float off = aT;
        #pragma unroll
        for (int s = 1; s < 16; s <<= 1) {
            float t2 = __shfl_down(off, s);
            if (lane + s < chunk) off += t2;
        }
        if (lane < chunk) mf += off;   // convert to this chunk's local frame
        // tree-combine lanes 0..15 (softmax merge; -1e30 is identity)
        #pragma unroll
        for (int s = 1; s < 16; s <<= 1) {
            float m2 = __shfl_xor(mf, s);
            float d2 = __shfl_xor(dd, s);
            float mn = fmaxf(mf, m2);
            float al = __expf(mf - mn), be = __expf(m2 - mn);
            #pragma unroll
            for (int j = 0; j < 16; j++) {
                float n2 = __shfl_xor(nn[j], s);
                nn[j] = nn[j] * al + n2 * be;
            }
            dd = dd * al + d2 * be;
            mf = mn;
        }
        if (lane == 0) {
            s_pref[0] = mf; s_pref[1] = dd;
            #pragma unroll
            for (int j = 0; j < 16; j++) s_pref[2 + j] = nn[j];
        }
    }
    __syncthreads();

    // ---- combine prefix with per-row state, gate, write Ybf ----
    if (active) {
        const float M = s_pref[0], D = s_pref[1];
        const float mn = fmaxf(M, myM);
        const float al = __expf(M - mn), be = __expf(myM - mn);
        const float invd = 1.f / (D * al + d * be);

        const ushort_t* ct = &As[tid * 72];
        u16x8 g0 = *(const u16x8*)(ct + 48), g1 = *(const u16x8*)(ct + 56);
        u16x8 o0, o1;
        #pragma unroll
        for (int j = 0; j < 16; j++) {
            float Nj = s_pref[2 + j] * al + n[j] * be;
            float gpre = ((j < 8) ? bf2f(g0[j]) : bf2f(g1[j - 8])) + bg[h * 16 + j];
            float gate = 1.f / (1.f + __expf(-gpre));
            ushort_t yb = f2bf(Nj * invd * gate);
            if (j < 8) o0[j] = yb; else o1[j - 8] = yb;
        }
        const size_t row = (size_t)b * T_ + chunk * CHSZ_ + tid;
        *(u16x8*)(Ybf + row * 64 + h * 16)     = o0;
        *(u16x8*)(Ybf + row * 64 + h * 16 + 8) = o1;
    }
}

// ---------------------------------------------------------------------------
// Output GEMM: C(MxN) = A(MxK) @ BT(NxK)^T, bf16 MFMA. BM=64 BN=128 BK=64.
// ---------------------------------------------------------------------------
__global__ __launch_bounds__(256) void gemm_bt(const ushort_t* __restrict__ A,
                                               const ushort_t* __restrict__ BT,
                                               float* __restrict__ C,
                                               int M, int N, int K) {
    __shared__ ushort_t As[64 * 72];
    __shared__ ushort_t Bs[128 * 72];
    const int tid = threadIdx.x;
    const int wave = tid >> 6, lane = tid & 63;
    const int m0 = blockIdx.y * 64, n0 = blockIdx.x * 128;
    const int wr = wave >> 1, wc = wave & 1;

    fx4 acc[2][4];
    #pragma unroll
    for (int i = 0; i < 2; i++)
        #pragma unroll
        for (int j = 0; j < 4; j++) acc[i][j] = (fx4)0.f;

    const int sr = tid >> 3, sc = (tid & 7) * 8;

    for (int k0 = 0; k0 < K; k0 += 64) {
        #pragma unroll
        for (int s = 0; s < 2; s++) {
            int r = s * 32 + sr;
            *(u16x8*)&As[r * 72 + sc] = *(const u16x8*)(A + (size_t)(m0 + r) * K + k0 + sc);
        }
        #pragma unroll
        for (int s = 0; s < 4; s++) {
            int r = s * 32 + sr;
            *(u16x8*)&Bs[r * 72 + sc] = *(const u16x8*)(BT + (size_t)(n0 + r) * K + k0 + sc);
        }
        __syncthreads();
        const int fr = lane & 15, quad = lane >> 4;
        #pragma unroll
        for (int ks = 0; ks < 64; ks += 32) {
            bfx8 af[2], bfr[4];
            #pragma unroll
            for (int mi = 0; mi < 2; mi++)
                af[mi] = *(const bfx8*)&As[(wr * 32 + mi * 16 + fr) * 72 + ks + quad * 8];
            #pragma unroll
            for (int ni = 0; ni < 4; ni++)
                bfr[ni] = *(const bfx8*)&Bs[(wc * 64 + ni * 16 + fr) * 72 + ks + quad * 8];
            #pragma unroll
            for (int mi = 0; mi < 2; mi++)
                #pragma unroll
                for (int ni = 0; ni < 4; ni++)
                    acc[mi][ni] = __builtin_amdgcn_mfma_f32_16x16x32_bf16(af[mi], bfr[ni], acc[mi][ni], 0, 0, 0);
        }
        __syncthreads();
    }

    const int fr = lane & 15, quad = lane >> 4;
    #pragma unroll
    for (int mi = 0; mi < 2; mi++)
        #pragma unroll
        for (int ni = 0; ni < 4; ni++)
            #pragma unroll
            for (int r = 0; r < 4; r++) {
                int rr = m0 + wr * 32 + mi * 16 + quad * 4 + r;
                int cc = n0 + wc * 64 + ni * 16 + fr;
                C[(size_t)rr * N + cc] = acc[mi][ni][r];
            }
}

// ---------------------------------------------------------------------------
extern "C" void kernel_launch(void* const* d_in, const int* in_sizes, int n_in,
                              void* d_out, int out_size, void* d_ws, size_t ws_size,
                              hipStream_t stream) {
    const float* x  = (const float*)d_in[0];
    const float* Wq = (const float*)d_in[1];
    const float* Wk = (const float*)d_in[2];
    const float* Wv = (const float*)d_in[3];
    const float* Wa = (const float*)d_in[4];
    const float* ba = (const float*)d_in[5];
    const float* Wg = (const float*)d_in[6];
    const float* bg = (const float*)d_in[7];
    const float* Wo = (const float*)d_in[8];
    float* out = (float*)d_out;

    char* w = (char*)d_ws;
    ushort_t* xbf    = (ushort_t*)w;  w += (size_t)ROWS_ * D_ * 2;   // 8 MiB
    ushort_t* WcatT2 = (ushort_t*)w;  w += 256 * 512 * 2;            // 256 KiB
    ushort_t* WoT    = (ushort_t*)w;  w += 512 * 64 * 2;             // 64 KiB
    float*    Aarr   = (float*)w;     w += (size_t)ROWS_ * 4 * 4;    // 128 KiB
    float*    slots  = (float*)w;     w += 256 * 20 * 4;             // 20 KiB
    int*      flags  = (int*)w;       w += 256 * 4;                  // 1 KiB
    ushort_t* Ybf    = (ushort_t*)w;  w += (size_t)ROWS_ * 64 * 2;   // 1 MiB

    prep_pack<<<2689, 256, 0, stream>>>(x, Wa, ba, Wq, Wk, Wv, Wg, Wo,
                                        xbf, Aarr, WcatT2, WoT, flags);
    gemm_scan<<<256, 256, 0, stream>>>(xbf, WcatT2, Aarr, bg, slots, flags, Ybf);
    gemm_bt<<<dim3(4, 128), 256, 0, stream>>>(Ybf, WoT, out, ROWS_, D_, 64);
}

// Round 7
// 117.984 us; speedup vs baseline: 1.1342x; 1.0152x over previous
//
#include <hip/hip_runtime.h>
#include <math.h>

// Problem constants
#define B_    4
#define T_    2048
#define D_    512
#define H_    4
#define ROWS_ 8192
#define CHSZ_ 128     // timesteps per chunk
#define NCHK_ 16      // chunks per (b,h)

typedef unsigned short ushort_t;
typedef unsigned int   uint_t;
typedef __attribute__((ext_vector_type(8))) __bf16         bfx8;
typedef __attribute__((ext_vector_type(8))) unsigned short u16x8;
typedef __attribute__((ext_vector_type(4))) float          fx4;

__device__ __forceinline__ ushort_t f2bf(float f) {
    union { float f; uint_t u; } v; v.f = f;
    return (ushort_t)((v.u + 0x7FFFu + ((v.u >> 16) & 1u)) >> 16);
}
__device__ __forceinline__ float bf2f(ushort_t u) {
    union { uint_t u; float f; } v; v.u = ((uint_t)u) << 16; return v.f;
}

// ---------------------------------------------------------------------------
// prep_pack: blocks [0,2048): per-wave row prep (x->xbf bf16, fp32-exact
// a = -softplus(x·Wa+ba)); blocks [2048,2688): weight pack (head-major WcatT2,
// transposed WoT).
// ---------------------------------------------------------------------------
__global__ __launch_bounds__(256) void prep_pack(const float* __restrict__ x,
                                                 const float* __restrict__ Wa,
                                                 const float* __restrict__ ba,
                                                 const float* __restrict__ Wq,
                                                 const float* __restrict__ Wk,
                                                 const float* __restrict__ Wv,
                                                 const float* __restrict__ Wg,
                                                 const float* __restrict__ Wo,
                                                 ushort_t* __restrict__ xbf,
                                                 float* __restrict__ Aarr,
                                                 ushort_t* __restrict__ WcatT2,
                                                 ushort_t* __restrict__ WoT) {
    const int blk = blockIdx.x;
    if (blk < 2048) {
        const int wave = threadIdx.x >> 6, lane = threadIdx.x & 63;
        const int row = blk * 4 + wave;
        const float* xp = x + (size_t)row * D_ + lane * 8;
        float4 f0 = *(const float4*)xp;
        float4 f1 = *(const float4*)(xp + 4);
        float xv[8] = {f0.x, f0.y, f0.z, f0.w, f1.x, f1.y, f1.z, f1.w};

        u16x8 u;
        #pragma unroll
        for (int j = 0; j < 8; j++) u[j] = f2bf(xv[j]);
        *(u16x8*)(xbf + (size_t)row * D_ + lane * 8) = u;

        float a0 = 0.f, a1 = 0.f, a2 = 0.f, a3 = 0.f;
        #pragma unroll
        for (int j = 0; j < 8; j++) {
            float4 w = *(const float4*)&Wa[(size_t)(lane * 8 + j) * 4];
            a0 = fmaf(xv[j], w.x, a0);
            a1 = fmaf(xv[j], w.y, a1);
            a2 = fmaf(xv[j], w.z, a2);
            a3 = fmaf(xv[j], w.w, a3);
        }
        #pragma unroll
        for (int off = 32; off; off >>= 1) {
            a0 += __shfl_xor(a0, off);
            a1 += __shfl_xor(a1, off);
            a2 += __shfl_xor(a2, off);
            a3 += __shfl_xor(a3, off);
        }
        if (lane == 0) {
            float z[4] = {a0 + ba[0], a1 + ba[1], a2 + ba[2], a3 + ba[3]};
            float r[4];
            #pragma unroll
            for (int h = 0; h < 4; h++)
                r[h] = -(fmaxf(z[h], 0.f) + log1pf(expf(-fabsf(z[h]))));
            *(float4*)&Aarr[(size_t)row * 4] = make_float4(r[0], r[1], r[2], r[3]);
        }
    } else {
        int idx = (blk - 2048) * 256 + threadIdx.x;
        if (idx < 256 * 512) {
            int n = idx >> 9, d = idx & 511;
            int h = n >> 6, r = n & 63, part = r >> 4, j = r & 15;
            int col = h * 16 + j;
            const float* W = (part == 0) ? Wq : (part == 1) ? Wk : (part == 2) ? Wv : Wg;
            WcatT2[idx] = f2bf(W[(size_t)d * 64 + col]);
        } else {
            int r = idx - 256 * 512;          // 0..32767 = n*64 + k
            int n = r >> 6, k = r & 63;
            WoT[r] = f2bf(Wo[(size_t)k * 512 + n]);
        }
    }
}

// ---------------------------------------------------------------------------
// gemm_scanA: fused projection GEMM (128x64 tile, K=512, register-prefetch
// software pipeline) + chunk-local scan. NO cross-block sync — per-row states
// and chunk summaries go to memory; kernel boundary is the barrier.
// Grid: 256 = 64 row-chunks x 4 heads (head in high bits: the 4 head-blocks
// of a chunk are 64 apart -> same XCD mod 8 -> shared L2 for xbf).
//
// Scan normalization: PER-WAVE max frame (lg increases ~0.7/step; a 128-row
// chunk frame underflows early rows). Per-row state written as (myM, d, n) —
// a valid online-softmax triple for scanBC's exact max-aware combine.
// ---------------------------------------------------------------------------
__global__ __launch_bounds__(256) void gemm_scanA(const ushort_t* __restrict__ xbf,
                                                  const ushort_t* __restrict__ WcatT2,
                                                  const float* __restrict__ Aarr,
                                                  float* __restrict__ stateWS,
                                                  float* __restrict__ chunkSum,
                                                  ushort_t* __restrict__ gBuf) {
    __shared__ ushort_t As[128 * 72];   // reused as Ct after K-loop
    __shared__ ushort_t Bs[64 * 72];
    __shared__ float s_a0;
    __shared__ float s_wmax[2];
    __shared__ float s_tot[17];

    const int rc = blockIdx.x & 63;     // row chunk (b*16 + chunk)
    const int h  = blockIdx.x >> 6;
    const int m0 = rc * 128;
    const int n0 = h * 64;
    const int b  = rc >> 4, chunk = rc & 15;
    const int bh = b * 4 + h;

    const int tid = threadIdx.x;
    const int wave = tid >> 6, lane = tid & 63;
    const int fr = lane & 15, quad = lane >> 4;
    const int sr = tid >> 3, sc = (tid & 7) * 8;

    fx4 acc[2][4];
    #pragma unroll
    for (int i = 0; i < 2; i++)
        #pragma unroll
        for (int j = 0; j < 4; j++) acc[i][j] = (fx4)0.f;

    // register-prefetch software pipeline over K (8 iterations of 64)
    u16x8 ra[4], rb[2];
    #pragma unroll
    for (int s = 0; s < 4; s++)
        ra[s] = *(const u16x8*)(xbf + (size_t)(m0 + s * 32 + sr) * D_ + sc);
    #pragma unroll
    for (int s = 0; s < 2; s++)
        rb[s] = *(const u16x8*)(WcatT2 + (size_t)(n0 + s * 32 + sr) * D_ + sc);

    for (int it = 0; it < 8; it++) {
        // commit prefetched regs to LDS
        #pragma unroll
        for (int s = 0; s < 4; s++) *(u16x8*)&As[(s * 32 + sr) * 72 + sc] = ra[s];
        #pragma unroll
        for (int s = 0; s < 2; s++) *(u16x8*)&Bs[(s * 32 + sr) * 72 + sc] = rb[s];
        __syncthreads();
        // issue next tile's global loads (latency hides behind MFMA below)
        if (it < 7) {
            const int k0 = (it + 1) * 64;
            #pragma unroll
            for (int s = 0; s < 4; s++)
                ra[s] = *(const u16x8*)(xbf + (size_t)(m0 + s * 32 + sr) * D_ + k0 + sc);
            #pragma unroll
            for (int s = 0; s < 2; s++)
                rb[s] = *(const u16x8*)(WcatT2 + (size_t)(n0 + s * 32 + sr) * D_ + k0 + sc);
        }
        // compute on the committed tile
        #pragma unroll
        for (int ks = 0; ks < 64; ks += 32) {
            bfx8 af[2], bfr[4];
            #pragma unroll
            for (int mi = 0; mi < 2; mi++)
                af[mi] = *(const bfx8*)&As[(wave * 32 + mi * 16 + fr) * 72 + ks + quad * 8];
            #pragma unroll
            for (int ni = 0; ni < 4; ni++)
                bfr[ni] = *(const bfx8*)&Bs[(ni * 16 + fr) * 72 + ks + quad * 8];
            #pragma unroll
            for (int mi = 0; mi < 2; mi++)
                #pragma unroll
                for (int ni = 0; ni < 4; ni++)
                    acc[mi][ni] = __builtin_amdgcn_mfma_f32_16x16x32_bf16(af[mi], bfr[ni], acc[mi][ni], 0, 0, 0);
        }
        __syncthreads();
    }

    // C-tile (bf16) into As-as-Ct: row_local x 72 stride, cols 0..63
    #pragma unroll
    for (int mi = 0; mi < 2; mi++)
        #pragma unroll
        for (int ni = 0; ni < 4; ni++)
            #pragma unroll
            for (int r = 0; r < 4; r++) {
                int rl = wave * 32 + mi * 16 + quad * 4 + r;
                int cl = ni * 16 + fr;
                As[rl * 72 + cl] = f2bf(acc[mi][ni][r]);
            }
    __syncthreads();

    // ---- chunk-local scan: threads 0..127 (waves 0,1), one per row ----
    const bool active = (tid < 128);
    float bid = 0.f, a = 0.f;
    float v[16];
    if (active) {
        const ushort_t* ct = &As[tid * 72];
        u16x8 q0 = *(const u16x8*)(ct +  0), q1 = *(const u16x8*)(ct +  8);
        u16x8 k0 = *(const u16x8*)(ct + 16), k1 = *(const u16x8*)(ct + 24);
        u16x8 v0 = *(const u16x8*)(ct + 32), v1 = *(const u16x8*)(ct + 40);
        #pragma unroll
        for (int j = 0; j < 8; j++) {
            bid = fmaf(bf2f(q0[j]), bf2f(k0[j]), bid);
            bid = fmaf(bf2f(q1[j]), bf2f(k1[j]), bid);
            v[j]     = bf2f(v0[j]);
            v[8 + j] = bf2f(v1[j]);
        }
        bid *= 0.25f;
        a = Aarr[(size_t)(m0 + tid) * 4 + h];
    }

    // cumA inclusive scan over 128 rows (2 waves + LDS bridge)
    float ca = a;
    #pragma unroll
    for (int off = 1; off < 64; off <<= 1) {
        float up = __shfl_up(ca, off);
        if (lane >= off) ca += up;
    }
    if (tid == 63) s_a0 = ca;
    __syncthreads();
    if (active && wave == 1) ca += s_a0;

    float lg = bid - ca;      // chunk-local log-weight (increases with t)

    // per-wave max Mw (frame for this wave's prefix sums)
    float Mw = active ? lg : -1e30f;
    #pragma unroll
    for (int off = 32; off; off >>= 1) Mw = fmaxf(Mw, __shfl_xor(Mw, off));
    if (active && lane == 0) s_wmax[wave] = Mw;
    __syncthreads();
    const float M0 = s_wmax[0], M1 = s_wmax[1];
    const float Mc = fmaxf(M0, M1);

    // plain prefix sums of (d, n[16]) = e^{lg-Mw} * (1, v) within wave
    float d = active ? __expf(lg - Mw) : 0.f;
    float n[16];
    #pragma unroll
    for (int j = 0; j < 16; j++) n[j] = d * v[j];
    #pragma unroll
    for (int off = 1; off < 64; off <<= 1) {
        float ud = __shfl_up(d, off);
        float un[16];
        #pragma unroll
        for (int j = 0; j < 16; j++) un[j] = __shfl_up(n[j], off);
        if (lane >= off) {
            d += ud;
            #pragma unroll
            for (int j = 0; j < 16; j++) n[j] += un[j];
        }
    }
    // wave-0 totals -> LDS (frame M0)
    if (tid == 63) {
        s_tot[0] = d;
        #pragma unroll
        for (int j = 0; j < 16; j++) s_tot[1 + j] = n[j];
    }
    __syncthreads();
    // wave-1 rows merge wave-0 totals (result frame Mc)
    if (active && wave == 1) {
        float al = __expf(M0 - Mc), be = __expf(M1 - Mc);
        d = s_tot[0] * al + d * be;
        #pragma unroll
        for (int j = 0; j < 16; j++) n[j] = s_tot[1 + j] * al + n[j] * be;
    }
    const float myM = (wave == 0) ? M0 : Mc;   // frame of this row's (d,n)

    // ---- write per-row state (myM,d,n: a valid online-softmax triple),
    //      g-tile, and chunk summary ----
    if (active) {
        const int t = chunk * CHSZ_ + tid;
        const size_t eidx = (size_t)bh * T_ + t;
        stateWS[eidx] = myM;
        stateWS[32768 + eidx] = d;
        #pragma unroll
        for (int j = 0; j < 16; j++) stateWS[(size_t)(2 + j) * 32768 + eidx] = n[j];

        const ushort_t* ct = &As[tid * 72];
        u16x8 g0 = *(const u16x8*)(ct + 48), g1 = *(const u16x8*)(ct + 56);
        *(u16x8*)(gBuf + eidx * 16)     = g0;
        *(u16x8*)(gBuf + eidx * 16 + 8) = g1;

        if (tid == 127) {
            float* cs = chunkSum + (size_t)(bh * NCHK_ + chunk) * 20;
            cs[0] = Mc; cs[1] = d;
            #pragma unroll
            for (int j = 0; j < 16; j++) cs[2 + j] = n[j];
            cs[18] = ca;   // chunk total of a
        }
    }
}

// ---------------------------------------------------------------------------
// scanBC: per (bh,chunk) block. Thread 0 builds the chunk-exclusive prefix
// sequentially from chunkSum (<=15 combines, L2-served), then all 128
// threads combine with their row state, normalize, gate, write Ybf.
// ---------------------------------------------------------------------------
__global__ __launch_bounds__(128) void scanBC(const float* __restrict__ stateWS,
                                              const float* __restrict__ chunkSum,
                                              const ushort_t* __restrict__ gBuf,
                                              const float* __restrict__ bg,
                                              ushort_t* __restrict__ Ybf) {
    __shared__ float sp[20];
    const int blk = blockIdx.x;
    const int bh = blk >> 4, chunk = blk & 15;
    const int b = bh >> 2, h = bh & 3;
    const int tid = threadIdx.x;

    if (tid == 0) {
        float M = -INFINITY, D = 0.f, N[16];
        #pragma unroll
        for (int j = 0; j < 16; j++) N[j] = 0.f;
        float pA = 0.f;
        for (int c = 0; c < chunk; c++) {
            const float* cs = chunkSum + (size_t)(bh * NCHK_ + c) * 20;
            float m = cs[0] - pA, d = cs[1];
            float mn = fmaxf(M, m);
            float al = __expf(M - mn), be = __expf(m - mn);
            D = D * al + d * be;
            #pragma unroll
            for (int j = 0; j < 16; j++) N[j] = N[j] * al + cs[2 + j] * be;
            M = mn;
            pA += cs[18];
        }
        sp[0] = M; sp[1] = D;
        #pragma unroll
        for (int j = 0; j < 16; j++) sp[2 + j] = N[j];
        sp[18] = pA;
    }
    __syncthreads();

    const int t = chunk * CHSZ_ + tid;
    const size_t eidx = (size_t)bh * T_ + t;
    float M = sp[0], D = sp[1], pA = sp[18];
    float m = stateWS[eidx] - pA;
    float d = stateWS[32768 + eidx];
    float mn = fmaxf(M, m);
    float al = __expf(M - mn), be = __expf(m - mn);
    float invd = 1.f / (D * al + d * be);

    u16x8 g0 = *(const u16x8*)(gBuf + eidx * 16);
    u16x8 g1 = *(const u16x8*)(gBuf + eidx * 16 + 8);
    u16x8 o0, o1;
    #pragma unroll
    for (int j = 0; j < 16; j++) {
        float Nj = sp[2 + j] * al + stateWS[(size_t)(2 + j) * 32768 + eidx] * be;
        float gpre = ((j < 8) ? bf2f(g0[j]) : bf2f(g1[j - 8])) + bg[h * 16 + j];
        float gate = 1.f / (1.f + __expf(-gpre));
        ushort_t yb = f2bf(Nj * invd * gate);
        if (j < 8) o0[j] = yb; else o1[j - 8] = yb;
    }
    const size_t row = (size_t)b * T_ + t;
    *(u16x8*)(Ybf + row * 64 + h * 16)     = o0;
    *(u16x8*)(Ybf + row * 64 + h * 16 + 8) = o1;
}

// ---------------------------------------------------------------------------
// Output GEMM: C(MxN) = A(MxK) @ BT(NxK)^T, bf16 MFMA. BM=64 BN=128 BK=64.
// ---------------------------------------------------------------------------
__global__ __launch_bounds__(256) void gemm_bt(const ushort_t* __restrict__ A,
                                               const ushort_t* __restrict__ BT,
                                               float* __restrict__ C,
                                               int M, int N, int K) {
    __shared__ ushort_t As[64 * 72];
    __shared__ ushort_t Bs[128 * 72];
    const int tid = threadIdx.x;
    const int wave = tid >> 6, lane = tid & 63;
    const int m0 = blockIdx.y * 64, n0 = blockIdx.x * 128;
    const int wr = wave >> 1, wc = wave & 1;

    fx4 acc[2][4];
    #pragma unroll
    for (int i = 0; i < 2; i++)
        #pragma unroll
        for (int j = 0; j < 4; j++) acc[i][j] = (fx4)0.f;

    const int sr = tid >> 3, sc = (tid & 7) * 8;

    for (int k0 = 0; k0 < K; k0 += 64) {
        #pragma unroll
        for (int s = 0; s < 2; s++) {
            int r = s * 32 + sr;
            *(u16x8*)&As[r * 72 + sc] = *(const u16x8*)(A + (size_t)(m0 + r) * K + k0 + sc);
        }
        #pragma unroll
        for (int s = 0; s < 4; s++) {
            int r = s * 32 + sr;
            *(u16x8*)&Bs[r * 72 + sc] = *(const u16x8*)(BT + (size_t)(n0 + r) * K + k0 + sc);
        }
        __syncthreads();
        const int fr = lane & 15, quad = lane >> 4;
        #pragma unroll
        for (int ks = 0; ks < 64; ks += 32) {
            bfx8 af[2], bfr[4];
            #pragma unroll
            for (int mi = 0; mi < 2; mi++)
                af[mi] = *(const bfx8*)&As[(wr * 32 + mi * 16 + fr) * 72 + ks + quad * 8];
            #pragma unroll
            for (int ni = 0; ni < 4; ni++)
                bfr[ni] = *(const bfx8*)&Bs[(wc * 64 + ni * 16 + fr) * 72 + ks + quad * 8];
            #pragma unroll
            for (int mi = 0; mi < 2; mi++)
                #pragma unroll
                for (int ni = 0; ni < 4; ni++)
                    acc[mi][ni] = __builtin_amdgcn_mfma_f32_16x16x32_bf16(af[mi], bfr[ni], acc[mi][ni], 0, 0, 0);
        }
        __syncthreads();
    }

    const int fr = lane & 15, quad = lane >> 4;
    #pragma unroll
    for (int mi = 0; mi < 2; mi++)
        #pragma unroll
        for (int ni = 0; ni < 4; ni++)
            #pragma unroll
            for (int r = 0; r < 4; r++) {
                int rr = m0 + wr * 32 + mi * 16 + quad * 4 + r;
                int cc = n0 + wc * 64 + ni * 16 + fr;
                C[(size_t)rr * N + cc] = acc[mi][ni][r];
            }
}

// ---------------------------------------------------------------------------
extern "C" void kernel_launch(void* const* d_in, const int* in_sizes, int n_in,
                              void* d_out, int out_size, void* d_ws, size_t ws_size,
                              hipStream_t stream) {
    const float* x  = (const float*)d_in[0];
    const float* Wq = (const float*)d_in[1];
    const float* Wk = (const float*)d_in[2];
    const float* Wv = (const float*)d_in[3];
    const float* Wa = (const float*)d_in[4];
    const float* ba = (const float*)d_in[5];
    const float* Wg = (const float*)d_in[6];
    const float* bg = (const float*)d_in[7];
    const float* Wo = (const float*)d_in[8];
    float* out = (float*)d_out;

    char* w = (char*)d_ws;
    ushort_t* xbf      = (ushort_t*)w;  w += (size_t)ROWS_ * D_ * 2;    // 8 MiB
    ushort_t* WcatT2   = (ushort_t*)w;  w += 256 * 512 * 2;             // 256 KiB
    ushort_t* WoT      = (ushort_t*)w;  w += 512 * 64 * 2;              // 64 KiB
    float*    Aarr     = (float*)w;     w += (size_t)ROWS_ * 4 * 4;     // 128 KiB
    float*    stateWS  = (float*)w;     w += (size_t)18 * 32768 * 4;    // 2.25 MiB
    float*    chunkSum = (float*)w;     w += 256 * 20 * 4;              // 20 KiB
    ushort_t* gBuf     = (ushort_t*)w;  w += (size_t)32768 * 16 * 2;    // 1 MiB
    ushort_t* Ybf      = (ushort_t*)w;  w += (size_t)ROWS_ * 64 * 2;    // 1 MiB

    prep_pack<<<2688, 256, 0, stream>>>(x, Wa, ba, Wq, Wk, Wv, Wg, Wo,
                                        xbf, Aarr, WcatT2, WoT);
    gemm_scanA<<<256, 256, 0, stream>>>(xbf, WcatT2, Aarr, stateWS, chunkSum, gBuf);
    scanBC<<<256, 128, 0, stream>>>(stateWS, chunkSum, gBuf, bg, Ybf);
    gemm_bt<<<dim3(4, 128), 256, 0, stream>>>(Ybf, WoT, out, ROWS_, D_, 64);
}

// Round 8
// 111.485 us; speedup vs baseline: 1.2003x; 1.0583x over previous
//
#include <hip/hip_runtime.h>
#include <math.h>

// Problem constants
#define B_    4
#define T_    2048
#define D_    512
#define H_    4
#define ROWS_ 8192
#define CHSZ_ 128     // timesteps per chunk
#define NCHK_ 16      // chunks per (b,h)

typedef unsigned short ushort_t;
typedef unsigned int   uint_t;
typedef __attribute__((ext_vector_type(8))) __bf16         bfx8;
typedef __attribute__((ext_vector_type(8))) unsigned short u16x8;
typedef __attribute__((ext_vector_type(4))) float          fx4;

__device__ __forceinline__ ushort_t f2bf(float f) {
    union { float f; uint_t u; } v; v.f = f;
    return (ushort_t)((v.u + 0x7FFFu + ((v.u >> 16) & 1u)) >> 16);
}
__device__ __forceinline__ float bf2f(ushort_t u) {
    union { uint_t u; float f; } v; v.u = ((uint_t)u) << 16; return v.f;
}

// ---------------------------------------------------------------------------
// prep_pack: blocks [0,2048): per-wave row prep (x->xbf bf16, fp32-exact
// a = -softplus(x·Wa+ba)); blocks [2048,2688): weight pack (head-major WcatT2,
// transposed WoT).
// ---------------------------------------------------------------------------
__global__ __launch_bounds__(256) void prep_pack(const float* __restrict__ x,
                                                 const float* __restrict__ Wa,
                                                 const float* __restrict__ ba,
                                                 const float* __restrict__ Wq,
                                                 const float* __restrict__ Wk,
                                                 const float* __restrict__ Wv,
                                                 const float* __restrict__ Wg,
                                                 const float* __restrict__ Wo,
                                                 ushort_t* __restrict__ xbf,
                                                 float* __restrict__ Aarr,
                                                 ushort_t* __restrict__ WcatT2,
                                                 ushort_t* __restrict__ WoT) {
    const int blk = blockIdx.x;
    if (blk < 2048) {
        const int wave = threadIdx.x >> 6, lane = threadIdx.x & 63;
        const int row = blk * 4 + wave;
        const float* xp = x + (size_t)row * D_ + lane * 8;
        float4 f0 = *(const float4*)xp;
        float4 f1 = *(const float4*)(xp + 4);
        float xv[8] = {f0.x, f0.y, f0.z, f0.w, f1.x, f1.y, f1.z, f1.w};

        u16x8 u;
        #pragma unroll
        for (int j = 0; j < 8; j++) u[j] = f2bf(xv[j]);
        *(u16x8*)(xbf + (size_t)row * D_ + lane * 8) = u;

        float a0 = 0.f, a1 = 0.f, a2 = 0.f, a3 = 0.f;
        #pragma unroll
        for (int j = 0; j < 8; j++) {
            float4 w = *(const float4*)&Wa[(size_t)(lane * 8 + j) * 4];
            a0 = fmaf(xv[j], w.x, a0);
            a1 = fmaf(xv[j], w.y, a1);
            a2 = fmaf(xv[j], w.z, a2);
            a3 = fmaf(xv[j], w.w, a3);
        }
        #pragma unroll
        for (int off = 32; off; off >>= 1) {
            a0 += __shfl_xor(a0, off);
            a1 += __shfl_xor(a1, off);
            a2 += __shfl_xor(a2, off);
            a3 += __shfl_xor(a3, off);
        }
        if (lane == 0) {
            float z[4] = {a0 + ba[0], a1 + ba[1], a2 + ba[2], a3 + ba[3]};
            float r[4];
            #pragma unroll
            for (int h = 0; h < 4; h++)
                r[h] = -(fmaxf(z[h], 0.f) + log1pf(expf(-fabsf(z[h]))));
            *(float4*)&Aarr[(size_t)row * 4] = make_float4(r[0], r[1], r[2], r[3]);
        }
    } else {
        int idx = (blk - 2048) * 256 + threadIdx.x;
        if (idx < 256 * 512) {
            int n = idx >> 9, d = idx & 511;
            int h = n >> 6, r = n & 63, part = r >> 4, j = r & 15;
            int col = h * 16 + j;
            const float* W = (part == 0) ? Wq : (part == 1) ? Wk : (part == 2) ? Wv : Wg;
            WcatT2[idx] = f2bf(W[(size_t)d * 64 + col]);
        } else {
            int r = idx - 256 * 512;          // 0..32767 = n*64 + k
            int n = r >> 6, k = r & 63;
            WoT[r] = f2bf(Wo[(size_t)k * 512 + n]);
        }
    }
}

// ---------------------------------------------------------------------------
// gemm_scanA: fused projection GEMM (128x64 tile, K=512, register-prefetch
// software pipeline) + chunk-local scan. Per-row states (per-wave-max frame),
// chunk summaries, and the g-tile go to memory; kernel boundary = barrier.
// Grid: 256 = 64 row-chunks x 4 heads (head in high bits for xbf L2 reuse).
// ---------------------------------------------------------------------------
__global__ __launch_bounds__(256) void gemm_scanA(const ushort_t* __restrict__ xbf,
                                                  const ushort_t* __restrict__ WcatT2,
                                                  const float* __restrict__ Aarr,
                                                  float* __restrict__ stateWS,
                                                  float* __restrict__ chunkSum,
                                                  ushort_t* __restrict__ gBuf) {
    __shared__ ushort_t As[128 * 72];   // reused as Ct after K-loop
    __shared__ ushort_t Bs[64 * 72];
    __shared__ float s_a0;
    __shared__ float s_wmax[2];
    __shared__ float s_tot[17];

    const int rc = blockIdx.x & 63;     // row chunk (b*16 + chunk)
    const int h  = blockIdx.x >> 6;
    const int m0 = rc * 128;
    const int n0 = h * 64;
    const int b  = rc >> 4, chunk = rc & 15;
    const int bh = b * 4 + h;

    const int tid = threadIdx.x;
    const int wave = tid >> 6, lane = tid & 63;
    const int fr = lane & 15, quad = lane >> 4;
    const int sr = tid >> 3, sc = (tid & 7) * 8;

    fx4 acc[2][4];
    #pragma unroll
    for (int i = 0; i < 2; i++)
        #pragma unroll
        for (int j = 0; j < 4; j++) acc[i][j] = (fx4)0.f;

    // register-prefetch software pipeline over K (8 iterations of 64)
    u16x8 ra[4], rb[2];
    #pragma unroll
    for (int s = 0; s < 4; s++)
        ra[s] = *(const u16x8*)(xbf + (size_t)(m0 + s * 32 + sr) * D_ + sc);
    #pragma unroll
    for (int s = 0; s < 2; s++)
        rb[s] = *(const u16x8*)(WcatT2 + (size_t)(n0 + s * 32 + sr) * D_ + sc);

    for (int it = 0; it < 8; it++) {
        #pragma unroll
        for (int s = 0; s < 4; s++) *(u16x8*)&As[(s * 32 + sr) * 72 + sc] = ra[s];
        #pragma unroll
        for (int s = 0; s < 2; s++) *(u16x8*)&Bs[(s * 32 + sr) * 72 + sc] = rb[s];
        __syncthreads();
        if (it < 7) {
            const int k0 = (it + 1) * 64;
            #pragma unroll
            for (int s = 0; s < 4; s++)
                ra[s] = *(const u16x8*)(xbf + (size_t)(m0 + s * 32 + sr) * D_ + k0 + sc);
            #pragma unroll
            for (int s = 0; s < 2; s++)
                rb[s] = *(const u16x8*)(WcatT2 + (size_t)(n0 + s * 32 + sr) * D_ + k0 + sc);
        }
        #pragma unroll
        for (int ks = 0; ks < 64; ks += 32) {
            bfx8 af[2], bfr[4];
            #pragma unroll
            for (int mi = 0; mi < 2; mi++)
                af[mi] = *(const bfx8*)&As[(wave * 32 + mi * 16 + fr) * 72 + ks + quad * 8];
            #pragma unroll
            for (int ni = 0; ni < 4; ni++)
                bfr[ni] = *(const bfx8*)&Bs[(ni * 16 + fr) * 72 + ks + quad * 8];
            #pragma unroll
            for (int mi = 0; mi < 2; mi++)
                #pragma unroll
                for (int ni = 0; ni < 4; ni++)
                    acc[mi][ni] = __builtin_amdgcn_mfma_f32_16x16x32_bf16(af[mi], bfr[ni], acc[mi][ni], 0, 0, 0);
        }
        __syncthreads();
    }

    // C-tile (bf16) into As-as-Ct: row_local x 72 stride, cols 0..63
    #pragma unroll
    for (int mi = 0; mi < 2; mi++)
        #pragma unroll
        for (int ni = 0; ni < 4; ni++)
            #pragma unroll
            for (int r = 0; r < 4; r++) {
                int rl = wave * 32 + mi * 16 + quad * 4 + r;
                int cl = ni * 16 + fr;
                As[rl * 72 + cl] = f2bf(acc[mi][ni][r]);
            }
    __syncthreads();

    // ---- chunk-local scan: threads 0..127 (waves 0,1), one per row ----
    const bool active = (tid < 128);
    float bid = 0.f, a = 0.f;
    float v[16];
    if (active) {
        const ushort_t* ct = &As[tid * 72];
        u16x8 q0 = *(const u16x8*)(ct +  0), q1 = *(const u16x8*)(ct +  8);
        u16x8 k0 = *(const u16x8*)(ct + 16), k1 = *(const u16x8*)(ct + 24);
        u16x8 v0 = *(const u16x8*)(ct + 32), v1 = *(const u16x8*)(ct + 40);
        #pragma unroll
        for (int j = 0; j < 8; j++) {
            bid = fmaf(bf2f(q0[j]), bf2f(k0[j]), bid);
            bid = fmaf(bf2f(q1[j]), bf2f(k1[j]), bid);
            v[j]     = bf2f(v0[j]);
            v[8 + j] = bf2f(v1[j]);
        }
        bid *= 0.25f;
        a = Aarr[(size_t)(m0 + tid) * 4 + h];
    }

    // cumA inclusive scan over 128 rows (2 waves + LDS bridge)
    float ca = a;
    #pragma unroll
    for (int off = 1; off < 64; off <<= 1) {
        float up = __shfl_up(ca, off);
        if (lane >= off) ca += up;
    }
    if (tid == 63) s_a0 = ca;
    __syncthreads();
    if (active && wave == 1) ca += s_a0;

    float lg = bid - ca;      // chunk-local log-weight (increases with t)

    // per-wave max Mw (frame for this wave's prefix sums)
    float Mw = active ? lg : -1e30f;
    #pragma unroll
    for (int off = 32; off; off >>= 1) Mw = fmaxf(Mw, __shfl_xor(Mw, off));
    if (active && lane == 0) s_wmax[wave] = Mw;
    __syncthreads();
    const float M0 = s_wmax[0], M1 = s_wmax[1];
    const float Mc = fmaxf(M0, M1);

    // plain prefix sums of (d, n[16]) = e^{lg-Mw} * (1, v) within wave
    float d = active ? __expf(lg - Mw) : 0.f;
    float n[16];
    #pragma unroll
    for (int j = 0; j < 16; j++) n[j] = d * v[j];
    #pragma unroll
    for (int off = 1; off < 64; off <<= 1) {
        float ud = __shfl_up(d, off);
        float un[16];
        #pragma unroll
        for (int j = 0; j < 16; j++) un[j] = __shfl_up(n[j], off);
        if (lane >= off) {
            d += ud;
            #pragma unroll
            for (int j = 0; j < 16; j++) n[j] += un[j];
        }
    }
    if (tid == 63) {
        s_tot[0] = d;
        #pragma unroll
        for (int j = 0; j < 16; j++) s_tot[1 + j] = n[j];
    }
    __syncthreads();
    if (active && wave == 1) {
        float al = __expf(M0 - Mc), be = __expf(M1 - Mc);
        d = s_tot[0] * al + d * be;
        #pragma unroll
        for (int j = 0; j < 16; j++) n[j] = s_tot[1 + j] * al + n[j] * be;
    }
    const float myM = (wave == 0) ? M0 : Mc;   // frame of this row's (d,n)

    // ---- write per-row state, g-tile, chunk summary ----
    if (active) {
        const int t = chunk * CHSZ_ + tid;
        const size_t eidx = (size_t)bh * T_ + t;
        stateWS[eidx] = myM;
        stateWS[32768 + eidx] = d;
        #pragma unroll
        for (int j = 0; j < 16; j++) stateWS[(size_t)(2 + j) * 32768 + eidx] = n[j];

        const ushort_t* ct = &As[tid * 72];
        u16x8 g0 = *(const u16x8*)(ct + 48), g1 = *(const u16x8*)(ct + 56);
        *(u16x8*)(gBuf + eidx * 16)     = g0;
        *(u16x8*)(gBuf + eidx * 16 + 8) = g1;

        if (tid == 127) {
            float* cs = chunkSum + (size_t)(bh * NCHK_ + chunk) * 20;
            cs[0] = Mc; cs[1] = d;
            #pragma unroll
            for (int j = 0; j < 16; j++) cs[2 + j] = n[j];
            cs[18] = ca;   // chunk total of a
        }
    }
}

// ---------------------------------------------------------------------------
// scan_gemm: fused scanBC + output GEMM. Grid (4, 128): block = 64 rows x
// 128 cols of out, K=64. Prologue: wave 0 runs the parallel look-back over
// chunkSum for ALL 4 heads (lane = h*16+p, width-16 shuffles — R6's proven
// combine); then all 256 threads (thread = (head, row)) combine their row
// state with the prefix, gate, and write the 64x64 Y-tile into LDS (bf16).
// Ybf never touches global memory. Then the standard MFMA GEMM vs WoT.
// ---------------------------------------------------------------------------
__global__ __launch_bounds__(256) void scan_gemm(const float* __restrict__ stateWS,
                                                 const float* __restrict__ chunkSum,
                                                 const ushort_t* __restrict__ gBuf,
                                                 const float* __restrict__ bg,
                                                 const ushort_t* __restrict__ WoT,
                                                 float* __restrict__ C) {
    __shared__ ushort_t Ys[64 * 72];
    __shared__ ushort_t Bs[128 * 72];
    __shared__ float s_pref[4][18];

    const int m0 = blockIdx.y * 64;     // global row base
    const int n0 = blockIdx.x * 128;    // output column base
    const int b  = m0 >> 11;            // batch
    const int tt = m0 & 2047;           // batch-local t of tile row 0
    const int chunk = tt >> 7;          // containing chunk (tile is half a chunk)

    const int tid = threadIdx.x;
    const int wave = tid >> 6, lane = tid & 63;

    // stage WoT rows n0..n0+127 (cols of Wo), K=64
    const int sr = tid >> 3, sc = (tid & 7) * 8;
    #pragma unroll
    for (int s = 0; s < 4; s++) {
        int rr = s * 32 + sr;
        *(u16x8*)&Bs[rr * 72 + sc] = *(const u16x8*)(WoT + (size_t)(n0 + rr) * 64 + sc);
    }

    // per-(head,row) state loads: head = wave, row = lane (coalesced per plane)
    const int h = wave, r = lane;
    const int bh = b * 4 + h;
    const size_t eidx = (size_t)bh * T_ + tt + r;
    float m_row = stateWS[eidx];
    float d_row = stateWS[32768 + eidx];
    float n_row[16];
    #pragma unroll
    for (int j = 0; j < 16; j++) n_row[j] = stateWS[(size_t)(2 + j) * 32768 + eidx];
    u16x8 g0 = *(const u16x8*)(gBuf + eidx * 16);
    u16x8 g1 = *(const u16x8*)(gBuf + eidx * 16 + 8);

    // wave 0: parallel look-back for all 4 heads (lane = hh*16 + p)
    if (wave == 0) {
        const int hh = lane >> 4, p = lane & 15;
        const int bhh = b * 4 + hh;
        float mf = -1e30f, dd = 0.f, aT = 0.f;
        float nn[16];
        #pragma unroll
        for (int j = 0; j < 16; j++) nn[j] = 0.f;
        if (p < chunk) {
            const float* cs = chunkSum + (size_t)(bhh * NCHK_ + p) * 20;
            mf = cs[0]; dd = cs[1];
            #pragma unroll
            for (int j = 0; j < 16; j++) nn[j] = cs[2 + j];
            aT = cs[18];
        }
        // suffix sums of aTot within the 16-lane head group
        float off = aT;
        #pragma unroll
        for (int s = 1; s < 16; s <<= 1) {
            float t2 = __shfl_down(off, s, 16);
            if (p + s < chunk) off += t2;
        }
        if (p < chunk) mf += off;   // shift into this chunk's local frame
        // tree-combine the 16 lanes of each head group
        #pragma unroll
        for (int s = 1; s < 16; s <<= 1) {
            float m2 = __shfl_xor(mf, s, 16);
            float d2 = __shfl_xor(dd, s, 16);
            float mx = fmaxf(mf, m2);
            float al = __expf(mf - mx), be = __expf(m2 - mx);
            #pragma unroll
            for (int j = 0; j < 16; j++) {
                float n2 = __shfl_xor(nn[j], s, 16);
                nn[j] = nn[j] * al + n2 * be;
            }
            dd = dd * al + d2 * be;
            mf = mx;
        }
        if (p == 0) {
            s_pref[hh][0] = mf; s_pref[hh][1] = dd;
            #pragma unroll
            for (int j = 0; j < 16; j++) s_pref[hh][2 + j] = nn[j];
        }
    }
    __syncthreads();

    // combine prefix with row state, gate, write Y-tile to LDS
    {
        const float M = s_pref[h][0], D = s_pref[h][1];
        const float mx = fmaxf(M, m_row);
        const float al = __expf(M - mx), be = __expf(m_row - mx);
        const float invd = 1.f / (D * al + d_row * be);
        u16x8 o0, o1;
        #pragma unroll
        for (int j = 0; j < 16; j++) {
            float Nj = s_pref[h][2 + j] * al + n_row[j] * be;
            float gpre = ((j < 8) ? bf2f(g0[j]) : bf2f(g1[j - 8])) + bg[h * 16 + j];
            float gate = 1.f / (1.f + __expf(-gpre));
            ushort_t yb = f2bf(Nj * invd * gate);
            if (j < 8) o0[j] = yb; else o1[j - 8] = yb;
        }
        *(u16x8*)&Ys[r * 72 + h * 16]     = o0;
        *(u16x8*)&Ys[r * 72 + h * 16 + 8] = o1;
    }
    __syncthreads();

    // GEMM: out-tile (64 x 128) = Ys (64 x 64) @ Bs(128 x 64)^T
    const int wr = wave >> 1, wc = wave & 1;
    const int fr = lane & 15, quad = lane >> 4;
    fx4 acc[2][4];
    #pragma unroll
    for (int i = 0; i < 2; i++)
        #pragma unroll
        for (int j = 0; j < 4; j++) acc[i][j] = (fx4)0.f;

    #pragma unroll
    for (int ks = 0; ks < 64; ks += 32) {
        bfx8 af[2], bfr[4];
        #pragma unroll
        for (int mi = 0; mi < 2; mi++)
            af[mi] = *(const bfx8*)&Ys[(wr * 32 + mi * 16 + fr) * 72 + ks + quad * 8];
        #pragma unroll
        for (int ni = 0; ni < 4; ni++)
            bfr[ni] = *(const bfx8*)&Bs[(wc * 64 + ni * 16 + fr) * 72 + ks + quad * 8];
        #pragma unroll
        for (int mi = 0; mi < 2; mi++)
            #pragma unroll
            for (int ni = 0; ni < 4; ni++)
                acc[mi][ni] = __builtin_amdgcn_mfma_f32_16x16x32_bf16(af[mi], bfr[ni], acc[mi][ni], 0, 0, 0);
    }

    #pragma unroll
    for (int mi = 0; mi < 2; mi++)
        #pragma unroll
        for (int ni = 0; ni < 4; ni++)
            #pragma unroll
            for (int rr = 0; rr < 4; rr++) {
                int orow = m0 + wr * 32 + mi * 16 + quad * 4 + rr;
                int ocol = n0 + wc * 64 + ni * 16 + fr;
                C[(size_t)orow * D_ + ocol] = acc[mi][ni][rr];
            }
}

// ---------------------------------------------------------------------------
extern "C" void kernel_launch(void* const* d_in, const int* in_sizes, int n_in,
                              void* d_out, int out_size, void* d_ws, size_t ws_size,
                              hipStream_t stream) {
    const float* x  = (const float*)d_in[0];
    const float* Wq = (const float*)d_in[1];
    const float* Wk = (const float*)d_in[2];
    const float* Wv = (const float*)d_in[3];
    const float* Wa = (const float*)d_in[4];
    const float* ba = (const float*)d_in[5];
    const float* Wg = (const float*)d_in[6];
    const float* bg = (const float*)d_in[7];
    const float* Wo = (const float*)d_in[8];
    float* out = (float*)d_out;

    char* w = (char*)d_ws;
    ushort_t* xbf      = (ushort_t*)w;  w += (size_t)ROWS_ * D_ * 2;    // 8 MiB
    ushort_t* WcatT2   = (ushort_t*)w;  w += 256 * 512 * 2;             // 256 KiB
    ushort_t* WoT      = (ushort_t*)w;  w += 512 * 64 * 2;              // 64 KiB
    float*    Aarr     = (float*)w;     w += (size_t)ROWS_ * 4 * 4;     // 128 KiB
    float*    stateWS  = (float*)w;     w += (size_t)18 * 32768 * 4;    // 2.25 MiB
    float*    chunkSum = (float*)w;     w += 256 * 20 * 4;              // 20 KiB
    ushort_t* gBuf     = (ushort_t*)w;  w += (size_t)32768 * 16 * 2;    // 1 MiB

    prep_pack<<<2688, 256, 0, stream>>>(x, Wa, ba, Wq, Wk, Wv, Wg, Wo,
                                        xbf, Aarr, WcatT2, WoT);
    gemm_scanA<<<256, 256, 0, stream>>>(xbf, WcatT2, Aarr, stateWS, chunkSum, gBuf);
    scan_gemm<<<dim3(4, 128), 256, 0, stream>>>(stateWS, chunkSum, gBuf, bg, WoT, out);
}